// Round 11
// baseline (444.134 us; speedup 1.0000x reference)
//
#include <hip/hip_runtime.h>
#include <math.h>

#define DMODEL 768
#define NHEAD 12
#define DKDIM 64
#define BB 2
#define SS 2048
#define MROWS (BB * SS)    // 4096
#define WELEM (DMODEL * DMODEL)  // 589824
#define CLEN 1024          // per-half K chunk (intra-block split)

typedef unsigned short bf16_t;
typedef __attribute__((ext_vector_type(8))) short s8;   // 8 bf16 = 4 VGPRs (MFMA A/B frag)
typedef __attribute__((ext_vector_type(4))) float f4;   // MFMA C/D frag

#define MFMA(a, b, c) __builtin_amdgcn_mfma_f32_16x16x32_bf16((a), (b), (c), 0, 0, 0)

__device__ __forceinline__ bf16_t f2bf(float f) {   // round-to-nearest-even
    unsigned u = __float_as_uint(f);
    u += 0x7fffu + ((u >> 16) & 1u);
    return (bf16_t)(u >> 16);
}
__device__ __forceinline__ unsigned pack2(float a, float b) {
    return (unsigned)f2bf(a) | ((unsigned)f2bf(b) << 16);
}
__device__ __forceinline__ s8 ldfrag(const bf16_t* p) {
    union { uint4 u; s8 s; } x;
    x.u = *(const uint4*)p;
    return x.s;
}

// stage 16 consecutive elements -> 2 x uint4 of packed bf16
__device__ __forceinline__ void ld_stage(const bf16_t* p, uint4& u0, uint4& u1) {
    u0 = *(const uint4*)p;
    u1 = *(const uint4*)(p + 8);
}
__device__ __forceinline__ void ld_stage(const float* p, uint4& u0, uint4& u1) {
    const float4 f0 = *(const float4*)p;
    const float4 f1 = *(const float4*)(p + 4);
    const float4 f2 = *(const float4*)(p + 8);
    const float4 f3 = *(const float4*)(p + 12);
    u0.x = pack2(f0.x, f0.y); u0.y = pack2(f0.z, f0.w);
    u0.z = pack2(f1.x, f1.y); u0.w = pack2(f1.z, f1.w);
    u1.x = pack2(f2.x, f2.y); u1.y = pack2(f2.z, f2.w);
    u1.z = pack2(f3.x, f3.y); u1.w = pack2(f3.z, f3.w);
}

// ---------------------------------------------------------------------------
// Weight prepass: fp32 -> bf16, 4 matrices of 768x768. grid (576, 4), 256 thr.
// ---------------------------------------------------------------------------
__global__ void cvt_weights(const float* __restrict__ W0, const float* __restrict__ W1,
                            const float* __restrict__ W2, const float* __restrict__ W3,
                            bf16_t* __restrict__ dst)
{
    const float* src = (blockIdx.y == 0) ? W0 : (blockIdx.y == 1) ? W1
                     : (blockIdx.y == 2) ? W2 : W3;
    bf16_t* d = dst + (size_t)blockIdx.y * WELEM;
    const int i = (blockIdx.x * 256 + threadIdx.x) * 4;
    const float4 v = *(const float4*)(src + i);
    ushort4 h;
    h.x = f2bf(v.x); h.y = f2bf(v.y); h.z = f2bf(v.z); h.w = f2bf(v.w);
    *(ushort4*)(d + i) = h;
}

// ---------------------------------------------------------------------------
// LDS-staged MFMA GEMM (round-8 verified). C = A @ W^T + bias.
// z==2 (V projection) writes C in TRANSPOSED attention layout Vt[b][h][d][s]
// so attention loads PV B-frags straight from global. grid (6, M/128, nz).
// ---------------------------------------------------------------------------
template<typename TA, typename TO>
__global__ __launch_bounds__(256) void gemm_tiled(
    const TA* __restrict__ A0, const TA* __restrict__ A1, const TA* __restrict__ A2,
    const bf16_t* __restrict__ W0, const bf16_t* __restrict__ W1, const bf16_t* __restrict__ W2,
    const float* __restrict__ bias0, const float* __restrict__ bias1, const float* __restrict__ bias2,
    TO* __restrict__ C0, TO* __restrict__ C1, TO* __restrict__ C2)
{
    __shared__ uint4 As4[128 * 4];   // 128 rows x 4 swizzled 16B blocks (8 KB)
    __shared__ uint4 Bs4[128 * 4];

    const int z = blockIdx.z;
    const TA*     A    = (z == 0) ? A0 : (z == 1) ? A1 : A2;
    const bf16_t* W    = (z == 0) ? W0 : (z == 1) ? W1 : W2;
    const float*  bias = (z == 0) ? bias0 : (z == 1) ? bias1 : bias2;
    TO*           C    = (z == 0) ? C0 : (z == 1) ? C1 : C2;

    const int tid  = threadIdx.x;
    const int lane = tid & 63;
    const int w    = tid >> 6;
    const int wm   = w & 1;
    const int wn   = w >> 1;
    const int l15  = lane & 15;
    const int quad = lane >> 4;
    const int m0   = blockIdx.y * 128;
    const int n0   = blockIdx.x * 128;

    const int srow  = tid >> 1;
    const int shalf = tid & 1;
    const int sw    = srow & 3;

    const TA*     aptr = A + (size_t)(m0 + srow) * DMODEL + shalf * 16;
    const bf16_t* wptr = W + (size_t)(n0 + srow) * DMODEL + shalf * 16;

    f4 acc[4][4];
    #pragma unroll
    for (int i = 0; i < 4; i++)
        #pragma unroll
        for (int j = 0; j < 4; j++)
            acc[i][j] = (f4){0.f, 0.f, 0.f, 0.f};

    for (int k0 = 0; k0 < DMODEL; k0 += 32) {
        uint4 au0, au1, bu0, bu1;
        ld_stage(aptr + k0, au0, au1);
        ld_stage(wptr + k0, bu0, bu1);
        __syncthreads();
        As4[srow * 4 + ((shalf * 2 + 0) ^ sw)] = au0;
        As4[srow * 4 + ((shalf * 2 + 1) ^ sw)] = au1;
        Bs4[srow * 4 + ((shalf * 2 + 0) ^ sw)] = bu0;
        Bs4[srow * 4 + ((shalf * 2 + 1) ^ sw)] = bu1;
        __syncthreads();

        s8 af[4], bf[4];
        #pragma unroll
        for (int t = 0; t < 4; t++) {
            const int ar = wm * 64 + t * 16 + l15;
            const int br = wn * 64 + t * 16 + l15;
            union { uint4 u; s8 s; } xa, xb;
            xa.u = As4[ar * 4 + (quad ^ (ar & 3))];
            xb.u = Bs4[br * 4 + (quad ^ (br & 3))];
            af[t] = xa.s;
            bf[t] = xb.s;
        }
        #pragma unroll
        for (int mt = 0; mt < 4; mt++)
            #pragma unroll
            for (int nt = 0; nt < 4; nt++)
                acc[mt][nt] = MFMA(af[mt], bf[nt], acc[mt][nt]);
    }

    #pragma unroll
    for (int mt = 0; mt < 4; mt++) {
        #pragma unroll
        for (int nt = 0; nt < 4; nt++) {
            const int col = n0 + wn * 64 + nt * 16 + l15;
            const float bb = bias[col];
            #pragma unroll
            for (int reg = 0; reg < 4; reg++) {
                const int row = m0 + wm * 64 + mt * 16 + quad * 4 + reg;
                const float val = acc[mt][nt][reg] + bb;
                if constexpr (sizeof(TO) == 2) {
                    if (z == 2) {
                        // Vt[b][h][d][s]: b=row>>11, s=row&2047, h=col>>6, d=col&63
                        C[((((size_t)(row >> 11) * NHEAD + (col >> 6)) * DKDIM
                            + (col & 63)) << 11) + (row & 2047)] = f2bf(val);
                    } else {
                        C[(size_t)row * DMODEL + col] = f2bf(val);
                    }
                } else {
                    C[(size_t)row * DMODEL + col] = val;
                }
            }
        }
    }
}

// ---------------------------------------------------------------------------
// Flash attention, INTRA-BLOCK K-split. 512 threads = 8 waves:
// wave w: q-rows [q0 + (w&3)*16, +16), K-chunk (w>>2) of [0,1024)/[1024,2048).
// Main loop barrier-free (Ps wave-local; K/Vt frags direct from global).
// Partials (fp32 O, m, l) meet in LDS; one barrier; 512-thr combine -> Ctx.
// LDS 51 KB -> 3 blocks/CU = 24 waves/CU (grid supplies exactly 3/CU).
// grid (S/64, H, B).
// ---------------------------------------------------------------------------
__global__ __launch_bounds__(512, 6) void attn_split(
    const bf16_t* __restrict__ Q, const bf16_t* __restrict__ K,
    const bf16_t* __restrict__ Vt, const int* __restrict__ mask,
    bf16_t* __restrict__ Ctx)
{
    __shared__ unsigned Ps[8][16][36];    // per-wave P, A-layout packed pairs
    __shared__ float    Op[8][16][64];    // per-wave unnormalized O (fp32)
    __shared__ float    Ml[8][16][2];     // per-wave (m, l)

    const int tid  = threadIdx.x;
    const int lane = tid & 63;
    const int w    = tid >> 6;           // 0..7
    const int wq   = w & 3;              // q-row group
    const int kbeg = (w >> 2) * CLEN;    // K chunk
    const int l15  = lane & 15;
    const int quad = lane >> 4;
    const int q0   = blockIdx.x * 64;
    const int h    = blockIdx.y;
    const int b    = blockIdx.z;
    const size_t base = ((size_t)b * SS) * DMODEL + (size_t)h * DKDIM;

    const bf16_t* qrow = Q + base + (size_t)(q0 + wq * 16 + l15) * DMODEL + quad * 8;
    const s8 qf0 = ldfrag(qrow);
    const s8 qf1 = ldfrag(qrow + 32);

    const bf16_t* vt = Vt + (((size_t)b * NHEAD + h) * DKDIM << 11);

    f4 oacc[4];
    float m_run[4], l_run[4];
    #pragma unroll
    for (int i = 0; i < 4; i++) {
        oacc[i] = (f4){0.f, 0.f, 0.f, 0.f};
        m_run[i] = -3.0e30f; l_run[i] = 0.0f;
    }

    const int* mrow = mask + (size_t)b * SS * SS + (size_t)(q0 + wq * 16 + quad * 4) * SS;

    for (int k0 = kbeg; k0 < kbeg + CLEN; k0 += 64) {
        // S = Q K^T (frags direct from global)
        f4 sacc[4];
        #pragma unroll
        for (int nt = 0; nt < 4; nt++) {
            const bf16_t* krow = K + base + (size_t)(k0 + nt * 16 + l15) * DMODEL + quad * 8;
            f4 zz = {0.f, 0.f, 0.f, 0.f};
            zz = MFMA(qf0, ldfrag(krow), zz);
            zz = MFMA(qf1, ldfrag(krow + 32), zz);
            sacc[nt] = zz;
        }

        // mask + online softmax
        float p[4][4];
        #pragma unroll
        for (int reg = 0; reg < 4; reg++) {
            float sv[4];
            #pragma unroll
            for (int nt = 0; nt < 4; nt++) {
                const int mk = mrow[(size_t)reg * SS + k0 + nt * 16 + l15];
                sv[nt] = mk ? sacc[nt][reg] * 0.125f : -1.0e9f;
            }
            float mx = fmaxf(fmaxf(sv[0], sv[1]), fmaxf(sv[2], sv[3]));
            mx = fmaxf(mx, __shfl_xor(mx, 1, 16));
            mx = fmaxf(mx, __shfl_xor(mx, 2, 16));
            mx = fmaxf(mx, __shfl_xor(mx, 4, 16));
            mx = fmaxf(mx, __shfl_xor(mx, 8, 16));

            const float m_new = fmaxf(m_run[reg], mx);
            const float alpha = __expf(m_run[reg] - m_new);
            float rs = 0.f;
            #pragma unroll
            for (int nt = 0; nt < 4; nt++) {
                p[reg][nt] = __expf(sv[nt] - m_new);
                rs += p[reg][nt];
            }
            rs += __shfl_xor(rs, 1, 16);
            rs += __shfl_xor(rs, 2, 16);
            rs += __shfl_xor(rs, 4, 16);
            rs += __shfl_xor(rs, 8, 16);

            l_run[reg] = l_run[reg] * alpha + rs;
            m_run[reg] = m_new;
            #pragma unroll
            for (int dt = 0; dt < 4; dt++) oacc[dt][reg] *= alpha;
        }

        // P (C-layout) -> Ps[w] (A-layout), wave-local LDS (no barrier)
        #pragma unroll
        for (int reg = 0; reg < 4; reg++) {
            #pragma unroll
            for (int nt = 0; nt < 4; nt++) {
                const float mine  = p[reg][nt];
                const float other = __shfl_xor(mine, 1, 16);
                if ((lane & 1) == 0)
                    Ps[w][quad * 4 + reg][nt * 8 + (l15 >> 1)] = pack2(mine, other);
            }
        }

        // O += P @ V  (Vt B-frags direct from global: 8 contiguous bf16)
        #pragma unroll
        for (int kt = 0; kt < 2; kt++) {
            union { uint4 u; s8 s; } pf;
            pf.u = *(const uint4*)&Ps[w][l15][kt * 16 + quad * 4];
            #pragma unroll
            for (int dt = 0; dt < 4; dt++) {
                const s8 vf = ldfrag(vt + (((size_t)(dt * 16 + l15)) << 11)
                                        + k0 + kt * 32 + quad * 8);
                oacc[dt] = MFMA(pf.s, vf, oacc[dt]);
            }
        }
    }

    // dump partials to LDS
    #pragma unroll
    for (int reg = 0; reg < 4; reg++) {
        const int r16 = quad * 4 + reg;
        if (l15 == 0) {
            Ml[w][r16][0] = m_run[reg];
            Ml[w][r16][1] = l_run[reg];
        }
        #pragma unroll
        for (int dt = 0; dt < 4; dt++)
            Op[w][r16][dt * 16 + l15] = oacc[dt][reg];
    }
    __syncthreads();

    // combine halves: thread t -> row = t>>3 (0..63), col group (t&7)*8
    {
        const int row  = tid >> 3;
        const int colg = (tid & 7) * 8;
        const int rw   = row >> 4;       // wave pair (rw, rw+4)
        const int r16  = row & 15;

        const float ma = Ml[rw][r16][0],     la = Ml[rw][r16][1];
        const float mb = Ml[rw + 4][r16][0], lb = Ml[rw + 4][r16][1];
        const float M  = fmaxf(ma, mb);
        const float wa = __expf(ma - M);
        const float wb = __expf(mb - M);
        const float inv = 1.0f / (wa * la + wb * lb);

        union { bf16_t h[8]; uint4 u; } out;
        #pragma unroll
        for (int i = 0; i < 8; i++)
            out.h[i] = f2bf((wa * Op[rw][r16][colg + i]
                           + wb * Op[rw + 4][r16][colg + i]) * inv);

        *(uint4*)(Ctx + ((size_t)b * SS + q0 + row) * DMODEL + h * DKDIM + colg) = out.u;
    }
}

// ---------------------------------------------------------------------------
extern "C" void kernel_launch(void* const* d_in, const int* in_sizes, int n_in,
                              void* d_out, int out_size, void* d_ws, size_t ws_size,
                              hipStream_t stream)
{
    const float* q    = (const float*)d_in[0];
    const float* k    = (const float*)d_in[1];
    const float* v    = (const float*)d_in[2];
    const int*   mask = (const int*)  d_in[3];
    const float* Wq   = (const float*)d_in[4];
    const float* bq   = (const float*)d_in[5];
    const float* Wk   = (const float*)d_in[6];
    const float* bk   = (const float*)d_in[7];
    const float* Wv   = (const float*)d_in[8];
    const float* bv   = (const float*)d_in[9];
    const float* Wo   = (const float*)d_in[10];
    const float* bo   = (const float*)d_in[11];
    float* out = (float*)d_out;

    // ws: Qp, Kp, Ctx, Vt planes + 4 bf16 weights = 29.87 MB (proven r7-r9)
    bf16_t* wsb = (bf16_t*)d_ws;
    const size_t plane = (size_t)MROWS * DMODEL;   // 3,145,728
    bf16_t* Qp  = wsb;
    bf16_t* Kp  = wsb + plane;
    bf16_t* Ctx = wsb + 2 * plane;
    bf16_t* Vt  = wsb + 3 * plane;                 // [B][H][64][2048]
    bf16_t* Wqb = wsb + 4 * plane;
    bf16_t* Wkb = Wqb + WELEM;
    bf16_t* Wvb = Wkb + WELEM;
    bf16_t* Wob = Wvb + WELEM;

    cvt_weights<<<dim3(WELEM / 1024, 4), 256, 0, stream>>>(Wq, Wk, Wv, Wo, Wqb);

    // fused Q/K/V projections (V written pre-transposed): grid (6, 32, 3)
    gemm_tiled<float, bf16_t><<<dim3(DMODEL / 128, MROWS / 128, 3), 256, 0, stream>>>(
        q, k, v, Wqb, Wkb, Wvb, bq, bk, bv, Qp, Kp, Vt);

    attn_split<<<dim3(SS / 64, NHEAD, BB), 512, 0, stream>>>(Qp, Kp, Vt, mask, Ctx);

    // output projection: grid (6, 32, 1)
    gemm_tiled<bf16_t, float><<<dim3(DMODEL / 128, MROWS / 128, 1), 256, 0, stream>>>(
        Ctx, Ctx, Ctx, Wob, Wob, Wob, bo, bo, bo, out, out, out);
}

// Round 12
// 365.903 us; speedup vs baseline: 1.2138x; 1.2138x over previous
//
#include <hip/hip_runtime.h>
#include <math.h>

#define DMODEL 768
#define NHEAD 12
#define DKDIM 64
#define BB 2
#define SS 2048
#define MROWS (BB * SS)    // 4096
#define WELEM (DMODEL * DMODEL)  // 589824
#define CLEN 1024          // per-group K chunk (intra-block split)

typedef unsigned short bf16_t;
typedef __attribute__((ext_vector_type(8))) short s8;   // 8 bf16 = 4 VGPRs (MFMA A/B frag)
typedef __attribute__((ext_vector_type(4))) float f4;   // MFMA C/D frag

#define MFMA(a, b, c) __builtin_amdgcn_mfma_f32_16x16x32_bf16((a), (b), (c), 0, 0, 0)

__device__ __forceinline__ bf16_t f2bf(float f) {   // round-to-nearest-even
    unsigned u = __float_as_uint(f);
    u += 0x7fffu + ((u >> 16) & 1u);
    return (bf16_t)(u >> 16);
}
__device__ __forceinline__ unsigned pack2(float a, float b) {
    return (unsigned)f2bf(a) | ((unsigned)f2bf(b) << 16);
}
__device__ __forceinline__ s8 ldfrag(const bf16_t* p) {
    union { uint4 u; s8 s; } x;
    x.u = *(const uint4*)p;
    return x.s;
}

// stage 16 consecutive elements -> 2 x uint4 of packed bf16
__device__ __forceinline__ void ld_stage(const bf16_t* p, uint4& u0, uint4& u1) {
    u0 = *(const uint4*)p;
    u1 = *(const uint4*)(p + 8);
}
__device__ __forceinline__ void ld_stage(const float* p, uint4& u0, uint4& u1) {
    const float4 f0 = *(const float4*)p;
    const float4 f1 = *(const float4*)(p + 4);
    const float4 f2 = *(const float4*)(p + 8);
    const float4 f3 = *(const float4*)(p + 12);
    u0.x = pack2(f0.x, f0.y); u0.y = pack2(f0.z, f0.w);
    u0.z = pack2(f1.x, f1.y); u0.w = pack2(f1.z, f1.w);
    u1.x = pack2(f2.x, f2.y); u1.y = pack2(f2.z, f2.w);
    u1.z = pack2(f3.x, f3.y); u1.w = pack2(f3.z, f3.w);
}

// ---------------------------------------------------------------------------
// Weight prepass: fp32 -> bf16, 4 matrices of 768x768. grid (576, 4), 256 thr.
// ---------------------------------------------------------------------------
__global__ void cvt_weights(const float* __restrict__ W0, const float* __restrict__ W1,
                            const float* __restrict__ W2, const float* __restrict__ W3,
                            bf16_t* __restrict__ dst)
{
    const float* src = (blockIdx.y == 0) ? W0 : (blockIdx.y == 1) ? W1
                     : (blockIdx.y == 2) ? W2 : W3;
    bf16_t* d = dst + (size_t)blockIdx.y * WELEM;
    const int i = (blockIdx.x * 256 + threadIdx.x) * 4;
    const float4 v = *(const float4*)(src + i);
    ushort4 h;
    h.x = f2bf(v.x); h.y = f2bf(v.y); h.z = f2bf(v.z); h.w = f2bf(v.w);
    *(ushort4*)(d + i) = h;
}

// ---------------------------------------------------------------------------
// Mask prepass: int32 [B,1,S,S] -> bit-packed [B][S][S/32] (1 bit per entry).
// grid 1024 x 256 thr; thread packs 32 consecutive ints.
// ---------------------------------------------------------------------------
__global__ void pack_mask(const int* __restrict__ m, unsigned* __restrict__ mb)
{
    const size_t o = ((size_t)blockIdx.x * 256 + threadIdx.x) * 32;
    unsigned bits = 0;
    #pragma unroll
    for (int i = 0; i < 8; i++) {
        const int4 v = *(const int4*)(m + o + i * 4);
        bits |= (v.x ? 1u : 0u) << (i * 4 + 0);
        bits |= (v.y ? 1u : 0u) << (i * 4 + 1);
        bits |= (v.z ? 1u : 0u) << (i * 4 + 2);
        bits |= (v.w ? 1u : 0u) << (i * 4 + 3);
    }
    mb[o >> 5] = bits;
}

// ---------------------------------------------------------------------------
// LDS-staged MFMA GEMM (round-8 verified, unchanged). C = A @ W^T + bias.
// grid (6, M/128, nz); z selects problem instance (fused QKV).
// ---------------------------------------------------------------------------
template<typename TA, typename TO>
__global__ __launch_bounds__(256) void gemm_tiled(
    const TA* __restrict__ A0, const TA* __restrict__ A1, const TA* __restrict__ A2,
    const bf16_t* __restrict__ W0, const bf16_t* __restrict__ W1, const bf16_t* __restrict__ W2,
    const float* __restrict__ bias0, const float* __restrict__ bias1, const float* __restrict__ bias2,
    TO* __restrict__ C0, TO* __restrict__ C1, TO* __restrict__ C2)
{
    __shared__ uint4 As4[128 * 4];   // 128 rows x 4 swizzled 16B blocks (8 KB)
    __shared__ uint4 Bs4[128 * 4];

    const int z = blockIdx.z;
    const TA*     A    = (z == 0) ? A0 : (z == 1) ? A1 : A2;
    const bf16_t* W    = (z == 0) ? W0 : (z == 1) ? W1 : W2;
    const float*  bias = (z == 0) ? bias0 : (z == 1) ? bias1 : bias2;
    TO*           C    = (z == 0) ? C0 : (z == 1) ? C1 : C2;

    const int tid  = threadIdx.x;
    const int lane = tid & 63;
    const int w    = tid >> 6;
    const int wm   = w & 1;
    const int wn   = w >> 1;
    const int l15  = lane & 15;
    const int quad = lane >> 4;
    const int m0   = blockIdx.y * 128;
    const int n0   = blockIdx.x * 128;

    const int srow  = tid >> 1;
    const int shalf = tid & 1;
    const int sw    = srow & 3;

    const TA*     aptr = A + (size_t)(m0 + srow) * DMODEL + shalf * 16;
    const bf16_t* wptr = W + (size_t)(n0 + srow) * DMODEL + shalf * 16;

    f4 acc[4][4];
    #pragma unroll
    for (int i = 0; i < 4; i++)
        #pragma unroll
        for (int j = 0; j < 4; j++)
            acc[i][j] = (f4){0.f, 0.f, 0.f, 0.f};

    for (int k0 = 0; k0 < DMODEL; k0 += 32) {
        uint4 au0, au1, bu0, bu1;
        ld_stage(aptr + k0, au0, au1);
        ld_stage(wptr + k0, bu0, bu1);
        __syncthreads();
        As4[srow * 4 + ((shalf * 2 + 0) ^ sw)] = au0;
        As4[srow * 4 + ((shalf * 2 + 1) ^ sw)] = au1;
        Bs4[srow * 4 + ((shalf * 2 + 0) ^ sw)] = bu0;
        Bs4[srow * 4 + ((shalf * 2 + 1) ^ sw)] = bu1;
        __syncthreads();

        s8 af[4], bf[4];
        #pragma unroll
        for (int t = 0; t < 4; t++) {
            const int ar = wm * 64 + t * 16 + l15;
            const int br = wn * 64 + t * 16 + l15;
            union { uint4 u; s8 s; } xa, xb;
            xa.u = As4[ar * 4 + (quad ^ (ar & 3))];
            xb.u = Bs4[br * 4 + (quad ^ (br & 3))];
            af[t] = xa.s;
            bf[t] = xb.s;
        }
        #pragma unroll
        for (int mt = 0; mt < 4; mt++)
            #pragma unroll
            for (int nt = 0; nt < 4; nt++)
                acc[mt][nt] = MFMA(af[mt], bf[nt], acc[mt][nt]);
    }

    #pragma unroll
    for (int mt = 0; mt < 4; mt++) {
        #pragma unroll
        for (int nt = 0; nt < 4; nt++) {
            const int col = n0 + wn * 64 + nt * 16 + l15;
            const float bb = bias[col];
            #pragma unroll
            for (int reg = 0; reg < 4; reg++) {
                const int row = m0 + wm * 64 + mt * 16 + quad * 4 + reg;
                const float val = acc[mt][nt][reg] + bb;
                TO* dst = C + (size_t)row * DMODEL + col;
                if constexpr (sizeof(TO) == 2) *dst = f2bf(val);
                else                           *dst = val;
            }
        }
    }
}

// ---------------------------------------------------------------------------
// Flash attention: intra-block K-split WITH shared cooperative V staging
// (the r8-proven pattern, 2 groups) + bit-packed mask (4 dwordx2 loads/iter
// instead of 16 dwords). 512 thr = 2 groups x 4 waves; wave w: q-rows
// [q0+(w&3)*16,+16), K chunk (w>>2). LDS aliased: main loop Vs(2x9.2K)+
// Ps(8x2.3K)=36.9 KB; epilogue reuses it as Op+Ml for the in-LDS combine.
// grid (S/64, H, B) = 768 blocks; 36.9 KB -> up to 4 blocks/CU.
// ---------------------------------------------------------------------------
__global__ __launch_bounds__(512, 6) void attn_split(
    const bf16_t* __restrict__ Q, const bf16_t* __restrict__ K,
    const bf16_t* __restrict__ V, const unsigned* __restrict__ mbits,
    bf16_t* __restrict__ Ctx)
{
    __shared__ __align__(16) unsigned char smem[36864];
    typedef unsigned vs_t[64][36];
    typedef unsigned ps_t[16][36];
    vs_t* Vs = (vs_t*)smem;                       // [2][64][36] = 18432 B
    ps_t* Ps = (ps_t*)(smem + 18432);             // [8][16][36] = 18432 B
    typedef float op_t[16][64];
    op_t*  Op = (op_t*)smem;                      // [8][16][64] = 32768 B (aliased)
    float* Ml = (float*)(smem + 32768);           // [8][16][2]  = 1024 B

    const int tid  = threadIdx.x;
    const int lane = tid & 63;
    const int w    = tid >> 6;           // 0..7
    const int wq   = w & 3;              // q-row group
    const int g    = w >> 2;             // K chunk group
    const int kbeg = g * CLEN;
    const int l15  = lane & 15;
    const int quad = lane >> 4;
    const int q0   = blockIdx.x * 64;
    const int h    = blockIdx.y;
    const int b    = blockIdx.z;
    const size_t base = ((size_t)b * SS) * DMODEL + (size_t)h * DKDIM;

    const bf16_t* qrow = Q + base + (size_t)(q0 + wq * 16 + l15) * DMODEL + quad * 8;
    const s8 qf0 = ldfrag(qrow);
    const s8 qf1 = ldfrag(qrow + 32);

    f4 oacc[4];
    float m_run[4], l_run[4];
    #pragma unroll
    for (int i = 0; i < 4; i++) {
        oacc[i] = (f4){0.f, 0.f, 0.f, 0.f};
        m_run[i] = -3.0e30f; l_run[i] = 0.0f;
    }

    // V staging role: group sg stages its own chunk's tile
    const int st  = tid & 255;
    const int sg  = tid >> 8;
    const int kp  = st & 31;
    const int oct = st >> 5;

    // bit-mask row base: row q0+wq*16+quad*4 (+reg), 64 words per row
    const unsigned* mrow = mbits + (((size_t)b * SS + q0 + wq * 16 + quad * 4) << 6);

    for (int k0 = 0; k0 < CLEN; k0 += 64) {
        // prefetch V rows for this group's tile
        const bf16_t* vrow = V + base + (size_t)(sg * CLEN + k0 + 2 * kp) * DMODEL + oct * 8;
        const uint4 va = *(const uint4*)vrow;
        const uint4 vb = *(const uint4*)(vrow + DMODEL);
        __syncthreads();                     // prev iteration's PV reads done
        {
            const unsigned short* pa = (const unsigned short*)&va;
            const unsigned short* pb = (const unsigned short*)&vb;
            #pragma unroll
            for (int i = 0; i < 8; i++)
                Vs[sg][oct * 8 + i][kp] = (unsigned)pa[i] | ((unsigned)pb[i] << 16);
        }

        const int kk = kbeg + k0;

        // S = Q K^T (frags direct from global)
        f4 sacc[4];
        #pragma unroll
        for (int nt = 0; nt < 4; nt++) {
            const bf16_t* krow = K + base + (size_t)(kk + nt * 16 + l15) * DMODEL + quad * 8;
            f4 zz = {0.f, 0.f, 0.f, 0.f};
            zz = MFMA(qf0, ldfrag(krow), zz);
            zz = MFMA(qf1, ldfrag(krow + 32), zz);
            sacc[nt] = zz;
        }

        // bit-mask + online softmax
        float p[4][4];
        #pragma unroll
        for (int reg = 0; reg < 4; reg++) {
            const uint2 bw = *(const uint2*)(mrow + (reg << 6) + (kk >> 5));
            float sv[4];
            #pragma unroll
            for (int nt = 0; nt < 4; nt++) {
                const unsigned word = (nt & 2) ? bw.y : bw.x;
                const unsigned keep = (word >> ((nt & 1) * 16 + l15)) & 1u;
                sv[nt] = keep ? sacc[nt][reg] * 0.125f : -1.0e9f;
            }
            float mx = fmaxf(fmaxf(sv[0], sv[1]), fmaxf(sv[2], sv[3]));
            mx = fmaxf(mx, __shfl_xor(mx, 1, 16));
            mx = fmaxf(mx, __shfl_xor(mx, 2, 16));
            mx = fmaxf(mx, __shfl_xor(mx, 4, 16));
            mx = fmaxf(mx, __shfl_xor(mx, 8, 16));

            const float m_new = fmaxf(m_run[reg], mx);
            const float alpha = __expf(m_run[reg] - m_new);
            float rs = 0.f;
            #pragma unroll
            for (int nt = 0; nt < 4; nt++) {
                p[reg][nt] = __expf(sv[nt] - m_new);
                rs += p[reg][nt];
            }
            rs += __shfl_xor(rs, 1, 16);
            rs += __shfl_xor(rs, 2, 16);
            rs += __shfl_xor(rs, 4, 16);
            rs += __shfl_xor(rs, 8, 16);

            l_run[reg] = l_run[reg] * alpha + rs;
            m_run[reg] = m_new;
            #pragma unroll
            for (int dt = 0; dt < 4; dt++) oacc[dt][reg] *= alpha;
        }

        // P (C-layout) -> Ps[w] (A-layout), wave-local
        #pragma unroll
        for (int reg = 0; reg < 4; reg++) {
            #pragma unroll
            for (int nt = 0; nt < 4; nt++) {
                const float mine  = p[reg][nt];
                const float other = __shfl_xor(mine, 1, 16);
                if ((lane & 1) == 0)
                    Ps[w][quad * 4 + reg][nt * 8 + (l15 >> 1)] = pack2(mine, other);
            }
        }
        __syncthreads();                     // Vs fully staged (all waves)

        // O += P @ V from group's shared Vs
        #pragma unroll
        for (int kt = 0; kt < 2; kt++) {
            union { uint4 u; s8 s; } pf;
            pf.u = *(const uint4*)&Ps[w][l15][kt * 16 + quad * 4];
            #pragma unroll
            for (int dt = 0; dt < 4; dt++) {
                union { uint4 u; s8 s; } vf;
                vf.u = *(const uint4*)&Vs[g][dt * 16 + l15][kt * 16 + quad * 4];
                oacc[dt] = MFMA(pf.s, vf.s, oacc[dt]);
            }
        }
    }

    __syncthreads();   // all PV reads done before aliasing smem as Op/Ml

    // dump partials
    #pragma unroll
    for (int reg = 0; reg < 4; reg++) {
        const int r16 = quad * 4 + reg;
        if (l15 == 0) {
            Ml[w * 32 + r16 * 2 + 0] = m_run[reg];
            Ml[w * 32 + r16 * 2 + 1] = l_run[reg];
        }
        #pragma unroll
        for (int dt = 0; dt < 4; dt++)
            Op[w][r16][dt * 16 + l15] = oacc[dt][reg];
    }
    __syncthreads();

    // combine halves: thread t -> row = t>>3 (0..63), col group (t&7)*8
    {
        const int row  = tid >> 3;
        const int colg = (tid & 7) * 8;
        const int rw   = row >> 4;       // wave pair (rw, rw+4)
        const int r16  = row & 15;

        const float ma = Ml[rw * 32 + r16 * 2 + 0];
        const float la = Ml[rw * 32 + r16 * 2 + 1];
        const float mb = Ml[(rw + 4) * 32 + r16 * 2 + 0];
        const float lb = Ml[(rw + 4) * 32 + r16 * 2 + 1];
        const float M  = fmaxf(ma, mb);
        const float wa = __expf(ma - M);
        const float wb = __expf(mb - M);
        const float inv = 1.0f / (wa * la + wb * lb);

        union { bf16_t hh[8]; uint4 u; } outv;
        #pragma unroll
        for (int i = 0; i < 8; i++)
            outv.hh[i] = f2bf((wa * Op[rw][r16][colg + i]
                             + wb * Op[rw + 4][r16][colg + i]) * inv);

        *(uint4*)(Ctx + ((size_t)b * SS + q0 + row) * DMODEL + h * DKDIM + colg) = outv.u;
    }
}

// ---------------------------------------------------------------------------
extern "C" void kernel_launch(void* const* d_in, const int* in_sizes, int n_in,
                              void* d_out, int out_size, void* d_ws, size_t ws_size,
                              hipStream_t stream)
{
    const float* q    = (const float*)d_in[0];
    const float* k    = (const float*)d_in[1];
    const float* v    = (const float*)d_in[2];
    const int*   mask = (const int*)  d_in[3];
    const float* Wq   = (const float*)d_in[4];
    const float* bq   = (const float*)d_in[5];
    const float* Wk   = (const float*)d_in[6];
    const float* bk   = (const float*)d_in[7];
    const float* Wv   = (const float*)d_in[8];
    const float* bv   = (const float*)d_in[9];
    const float* Wo   = (const float*)d_in[10];
    const float* bo   = (const float*)d_in[11];
    float* out = (float*)d_out;

    // ws: 4 bf16 planes (25.2 MB) + 4 bf16 weights (4.7 MB) + mask bits (1 MB)
    bf16_t* wsb = (bf16_t*)d_ws;
    const size_t plane = (size_t)MROWS * DMODEL;   // 3,145,728
    bf16_t* Qp  = wsb;
    bf16_t* Kp  = wsb + plane;
    bf16_t* Vp  = wsb + 2 * plane;
    bf16_t* Ctx = wsb + 3 * plane;
    bf16_t* Wqb = wsb + 4 * plane;
    bf16_t* Wkb = Wqb + WELEM;
    bf16_t* Wvb = Wkb + WELEM;
    bf16_t* Wob = Wvb + WELEM;
    unsigned* mb = (unsigned*)(Wob + WELEM);       // 262144 words = 1 MB

    cvt_weights<<<dim3(WELEM / 1024, 4), 256, 0, stream>>>(Wq, Wk, Wv, Wo, Wqb);
    pack_mask<<<1024, 256, 0, stream>>>(mask, mb);

    // fused Q/K/V projections: grid (6, 32, 3)
    gemm_tiled<float, bf16_t><<<dim3(DMODEL / 128, MROWS / 128, 3), 256, 0, stream>>>(
        q, k, v, Wqb, Wkb, Wvb, bq, bk, bv, Qp, Kp, Vp);

    attn_split<<<dim3(SS / 64, NHEAD, BB), 512, 0, stream>>>(Qp, Kp, Vp, mb, Ctx);

    // output projection: grid (6, 32, 1)
    gemm_tiled<bf16_t, float><<<dim3(DMODEL / 128, MROWS / 128, 1), 256, 0, stream>>>(
        Ctx, Ctx, Ctx, Wob, Wob, Wob, bo, bo, bo, out, out, out);
}